// Round 1
// baseline (1054.984 us; speedup 1.0000x reference)
//
#include <hip/hip_runtime.h>
#include <math.h>

// Problem constants
#define kN 50000
#define kE 800000
#define kM 4
#define kH 4
#define kC 32
#define kIN 256
#define kD 128   // kH*kC

// ---------------------------------------------------------------------------
// zero scratch counters
__global__ void k_zero(int* __restrict__ p, int n) {
    int i = blockIdx.x * blockDim.x + threadIdx.x;
    if (i < n) p[i] = 0;
}

// ---------------------------------------------------------------------------
// h[n][128] = relu(feats[n][256] @ W[256][128] + b)
// block 256 threads, tile 64 rows x 128 cols, k staged in chunks of 64
__global__ __launch_bounds__(256) void k_gemm(const float* __restrict__ feats,
                                              const float* __restrict__ W,
                                              const float* __restrict__ b,
                                              float* __restrict__ h) {
    __shared__ float fr[64][68];    // [row][k], pad 68 to break bank conflicts
    __shared__ float wc[64][128];   // [k][col]
    const int t = threadIdx.x;
    const int rowbase = blockIdx.x * 64;
    const int tr4 = (t >> 4) * 4;   // rows tr4..tr4+3
    const int tc = t & 15;          // cols tc*4..+3 and 64+tc*4..+3

    float acc[4][8];
#pragma unroll
    for (int i = 0; i < 4; i++)
#pragma unroll
        for (int j = 0; j < 8; j++) acc[i][j] = 0.f;

    for (int kc = 0; kc < kIN; kc += 64) {
        // stage feats chunk: 64 rows x 64 k
        {
            const int row = t >> 4;   // 0..15
            const int k4 = t & 15;    // 0..15
#pragma unroll
            for (int i = 0; i < 4; i++) {
                const int r = row + i * 16;
                const int rg = rowbase + r;
                float4 v = make_float4(0.f, 0.f, 0.f, 0.f);
                if (rg < kN)
                    v = *reinterpret_cast<const float4*>(feats + rg * kIN + kc + k4 * 4);
                *reinterpret_cast<float4*>(&fr[r][k4 * 4]) = v;
            }
        }
        // stage W chunk: 64 k x 128 cols
#pragma unroll
        for (int i = 0; i < 8; i++) {
            const int v4 = t + i * 256;   // 0..2047 float4 index
            const int kk = v4 >> 5;       // 0..63
            const int c4 = v4 & 31;       // 0..31
            *reinterpret_cast<float4*>(&wc[kk][c4 * 4]) =
                *reinterpret_cast<const float4*>(W + (size_t)(kc + kk) * kD + c4 * 4);
        }
        __syncthreads();

#pragma unroll 8
        for (int k = 0; k < 64; k++) {
            const float a0 = fr[tr4 + 0][k];
            const float a1 = fr[tr4 + 1][k];
            const float a2 = fr[tr4 + 2][k];
            const float a3 = fr[tr4 + 3][k];
            const float4 w0 = *reinterpret_cast<const float4*>(&wc[k][tc * 4]);
            const float4 w1 = *reinterpret_cast<const float4*>(&wc[k][64 + tc * 4]);
            acc[0][0] += a0 * w0.x; acc[0][1] += a0 * w0.y; acc[0][2] += a0 * w0.z; acc[0][3] += a0 * w0.w;
            acc[0][4] += a0 * w1.x; acc[0][5] += a0 * w1.y; acc[0][6] += a0 * w1.z; acc[0][7] += a0 * w1.w;
            acc[1][0] += a1 * w0.x; acc[1][1] += a1 * w0.y; acc[1][2] += a1 * w0.z; acc[1][3] += a1 * w0.w;
            acc[1][4] += a1 * w1.x; acc[1][5] += a1 * w1.y; acc[1][6] += a1 * w1.z; acc[1][7] += a1 * w1.w;
            acc[2][0] += a2 * w0.x; acc[2][1] += a2 * w0.y; acc[2][2] += a2 * w0.z; acc[2][3] += a2 * w0.w;
            acc[2][4] += a2 * w1.x; acc[2][5] += a2 * w1.y; acc[2][6] += a2 * w1.z; acc[2][7] += a2 * w1.w;
            acc[3][0] += a3 * w0.x; acc[3][1] += a3 * w0.y; acc[3][2] += a3 * w0.z; acc[3][3] += a3 * w0.w;
            acc[3][4] += a3 * w1.x; acc[3][5] += a3 * w1.y; acc[3][6] += a3 * w1.z; acc[3][7] += a3 * w1.w;
        }
        __syncthreads();
    }

    const float4 b0 = *reinterpret_cast<const float4*>(b + tc * 4);
    const float4 b1 = *reinterpret_cast<const float4*>(b + 64 + tc * 4);
#pragma unroll
    for (int i = 0; i < 4; i++) {
        const int rg = rowbase + tr4 + i;
        if (rg < kN) {
            float4 o0, o1;
            o0.x = fmaxf(acc[i][0] + b0.x, 0.f);
            o0.y = fmaxf(acc[i][1] + b0.y, 0.f);
            o0.z = fmaxf(acc[i][2] + b0.z, 0.f);
            o0.w = fmaxf(acc[i][3] + b0.w, 0.f);
            o1.x = fmaxf(acc[i][4] + b1.x, 0.f);
            o1.y = fmaxf(acc[i][5] + b1.y, 0.f);
            o1.z = fmaxf(acc[i][6] + b1.z, 0.f);
            o1.w = fmaxf(acc[i][7] + b1.w, 0.f);
            *reinterpret_cast<float4*>(h + (size_t)rg * kD + tc * 4) = o0;
            *reinterpret_cast<float4*>(h + (size_t)rg * kD + 64 + tc * 4) = o1;
        }
    }
}

// ---------------------------------------------------------------------------
// per-node attention scalars: sl[m][n][h] = h[n,h,:].attn[m,h,:C]
//                             sr[m][n][h] = h[n,h,:].attn[m,h,C:]
__global__ void k_slr(const float* __restrict__ h, const float* __restrict__ attn,
                      float* __restrict__ sl, float* __restrict__ sr) {
    const int id = blockIdx.x * blockDim.x + threadIdx.x;
    if (id >= kN * kH) return;
    const int n = id >> 2;
    const int hh = id & 3;
    float4 hx[8];
    const float4* hv = reinterpret_cast<const float4*>(h + (size_t)n * kD + hh * kC);
#pragma unroll
    for (int i = 0; i < 8; i++) hx[i] = hv[i];
#pragma unroll
    for (int m = 0; m < kM; m++) {
        const float4* al = reinterpret_cast<const float4*>(attn + (m * kH + hh) * 2 * kC);
        const float4* ar = al + 8;
        float s0 = 0.f, s1 = 0.f;
#pragma unroll
        for (int i = 0; i < 8; i++) {
            const float4 a = al[i], r = ar[i], x = hx[i];
            s0 += x.x * a.x + x.y * a.y + x.z * a.z + x.w * a.w;
            s1 += x.x * r.x + x.y * r.y + x.z * r.z + x.w * r.w;
        }
        sl[((size_t)m * kN + n) * kH + hh] = s0;
        sr[((size_t)m * kN + n) * kH + hh] = s1;
    }
}

// ---------------------------------------------------------------------------
// CSR build: degree count
__global__ void k_count(const int* __restrict__ ei, int* __restrict__ cnt) {
    const int e = blockIdx.x * blockDim.x + threadIdx.x;
    if (e >= kM * kE) return;
    const int m = e / kE;
    const int el = e - m * kE;
    const int dst = ei[(size_t)m * 2 * kE + kE + el];
    atomicAdd(&cnt[m * kN + dst], 1);
}

// exclusive scan per metapath (one block per m)
__global__ __launch_bounds__(1024) void k_scan(const int* __restrict__ cnt,
                                               int* __restrict__ offs) {
    const int m = blockIdx.x;
    const int* c = cnt + (size_t)m * kN;
    int* o = offs + (size_t)m * (kN + 1);
    __shared__ int wsum[16];
    __shared__ int carry_s;
    const int t = threadIdx.x;
    const int w = t >> 6, l = t & 63;
    if (t == 0) carry_s = 0;
    __syncthreads();
    for (int base = 0; base < kN; base += 4096) {
        const int i0 = base + t * 4;
        const int v0 = (i0 + 0 < kN) ? c[i0 + 0] : 0;
        const int v1 = (i0 + 1 < kN) ? c[i0 + 1] : 0;
        const int v2 = (i0 + 2 < kN) ? c[i0 + 2] : 0;
        const int v3 = (i0 + 3 < kN) ? c[i0 + 3] : 0;
        const int s = v0 + v1 + v2 + v3;
        int sc = s;
#pragma unroll
        for (int d = 1; d < 64; d <<= 1) {
            const int x = __shfl_up(sc, d);
            if (l >= d) sc += x;
        }
        if (l == 63) wsum[w] = sc;
        __syncthreads();
        int woff = 0, tot = 0;
#pragma unroll
        for (int i = 0; i < 16; i++) {
            const int v = wsum[i];
            tot += v;
            if (i < w) woff += v;
        }
        const int carry = carry_s;
        __syncthreads();
        if (t == 0) carry_s = carry + tot;
        int run = carry + woff + (sc - s);
        if (i0 + 0 < kN) o[i0 + 0] = run; run += v0;
        if (i0 + 1 < kN) o[i0 + 1] = run; run += v1;
        if (i0 + 2 < kN) o[i0 + 2] = run; run += v2;
        if (i0 + 3 < kN) o[i0 + 3] = run; run += v3;
    }
    if (t == 0) o[kN] = carry_s;
}

// scatter src ids into CSR order
__global__ void k_scatter(const int* __restrict__ ei, const int* __restrict__ offs,
                          int* __restrict__ cur, int* __restrict__ srcsort) {
    const int e = blockIdx.x * blockDim.x + threadIdx.x;
    if (e >= kM * kE) return;
    const int m = e / kE;
    const int el = e - m * kE;
    const int src = ei[(size_t)m * 2 * kE + el];
    const int dst = ei[(size_t)m * 2 * kE + kE + el];
    const int pos = offs[(size_t)m * (kN + 1) + dst] + atomicAdd(&cur[m * kN + dst], 1);
    srcsort[(size_t)m * kE + pos] = src;
}

// ---------------------------------------------------------------------------
// main: per-dst-node block; wave m = metapath m (GAT softmax+aggregate),
// then fused beta relation-attention epilogue on wave 0.
__global__ __launch_bounds__(256) void k_agg(const float* __restrict__ h,
                                             const float* __restrict__ sl,
                                             const float* __restrict__ sr,
                                             const int* __restrict__ offs,
                                             const int* __restrict__ srcsort,
                                             const float* __restrict__ ral,
                                             const float* __restrict__ rar,
                                             const float* __restrict__ rbias,
                                             float* __restrict__ out) {
    const int dst = blockIdx.x;
    const int t = threadIdx.x;
    const int m = t >> 6;
    const int l = t & 63;
    const int hh = l >> 4;        // head for this lane
    const int e0 = l * 2;         // element index (h*32+c), lane covers e0,e0+1

    __shared__ float sm[kM][kD];

    const int beg = offs[(size_t)m * (kN + 1) + dst];
    const int end = offs[(size_t)m * (kN + 1) + dst + 1];
    const float sl_h = sl[((size_t)m * kN + dst) * kH + hh];

    // pass 1: max logit per head
    float maxl = -1e30f;
    for (int i = beg; i < end; i++) {
        const int s = srcsort[(size_t)m * kE + i];
        float v = sl_h + sr[((size_t)m * kN + s) * kH + hh];
        v = v > 0.f ? v : 0.2f * v;
        maxl = fmaxf(maxl, v);
    }
    // pass 2: exp-sum + weighted feature gather
    float sum = 0.f, a0 = 0.f, a1 = 0.f;
    for (int i = beg; i < end; i++) {
        const int s = srcsort[(size_t)m * kE + i];
        float v = sl_h + sr[((size_t)m * kN + s) * kH + hh];
        v = v > 0.f ? v : 0.2f * v;
        const float wgt = __expf(v - maxl);
        const float2 hv = *reinterpret_cast<const float2*>(h + (size_t)s * kD + e0);
        sum += wgt;
        a0 += wgt * hv.x;
        a1 += wgt * hv.y;
    }
    const float inv = sum > 0.f ? 1.0f / sum : 0.f;
    sm[m][e0] = a0 * inv;
    sm[m][e0 + 1] = a1 * inv;
    __syncthreads();

    if (m == 0) {
        const float2 hd = *reinterpret_cast<const float2*>(h + (size_t)dst * kD + e0);
        const float bl0 = fmaxf(hd.x * ral[e0], 0.f);
        const float bl1 = fmaxf(hd.y * ral[e0 + 1], 0.f);
        float emb0[5], emb1[5], beta[5];
#pragma unroll
        for (int r = 0; r < 5; r++) {
            const float x0 = (r < 4) ? sm[r][e0] : hd.x;
            const float x1 = (r < 4) ? sm[r][e0 + 1] : hd.y;
            emb0[r] = x0;
            emb1[r] = x1;
            const float br0 = fmaxf(x0 * rar[r * kD + e0], 0.f);
            const float br1 = fmaxf(x1 * rar[r * kD + e0 + 1], 0.f);
            float p = bl0 * br0 + bl1 * br1;
            p += __shfl_xor(p, 1);
            p += __shfl_xor(p, 2);
            p += __shfl_xor(p, 4);
            p += __shfl_xor(p, 8);
            beta[r] = p + rbias[r];
        }
        float mx = beta[0];
#pragma unroll
        for (int r = 1; r < 5; r++) mx = fmaxf(mx, beta[r]);
        float s = 0.f, wgt[5];
#pragma unroll
        for (int r = 0; r < 5; r++) { wgt[r] = __expf(beta[r] - mx); s += wgt[r]; }
        const float invb = 1.f / s;
        float o0 = 0.f, o1 = 0.f;
#pragma unroll
        for (int r = 0; r < 5; r++) { o0 += emb0[r] * wgt[r]; o1 += emb1[r] * wgt[r]; }
        out[(size_t)dst * kD + e0] = fmaxf(o0 * invb, 0.f);
        out[(size_t)dst * kD + e0 + 1] = fmaxf(o1 * invb, 0.f);
    }
}

// ---------------------------------------------------------------------------
extern "C" void kernel_launch(void* const* d_in, const int* in_sizes, int n_in,
                              void* d_out, int out_size, void* d_ws, size_t ws_size,
                              hipStream_t stream) {
    const float* feats = (const float*)d_in[0];
    const int* ei      = (const int*)d_in[1];
    const float* W     = (const float*)d_in[2];
    const float* b     = (const float*)d_in[3];
    const float* attn  = (const float*)d_in[4];
    const float* ral   = (const float*)d_in[5];
    const float* rar   = (const float*)d_in[6];
    const float* rbias = (const float*)d_in[7];
    float* out = (float*)d_out;

    char* ws = (char*)d_ws;
    size_t off = 0;
    auto alloc = [&](size_t bytes) -> void* {
        void* p = ws + off;
        off = (off + bytes + 255) & ~(size_t)255;
        return p;
    };
    float* h    = (float*)alloc(sizeof(float) * (size_t)kN * kD);          // 25.6 MB
    float* sl   = (float*)alloc(sizeof(float) * (size_t)kM * kN * kH);     // 3.2 MB
    float* sr   = (float*)alloc(sizeof(float) * (size_t)kM * kN * kH);     // 3.2 MB
    int* cnt    = (int*)alloc(sizeof(int) * (size_t)2 * kM * kN);          // cnt+cur
    int* cur    = cnt + (size_t)kM * kN;
    int* offs   = (int*)alloc(sizeof(int) * (size_t)kM * (kN + 1));
    int* srcsort= (int*)alloc(sizeof(int) * (size_t)kM * kE);              // 12.8 MB

    k_zero<<<(2 * kM * kN + 255) / 256, 256, 0, stream>>>(cnt, 2 * kM * kN);
    k_gemm<<<(kN + 63) / 64, 256, 0, stream>>>(feats, W, b, h);
    k_slr<<<(kN * kH + 255) / 256, 256, 0, stream>>>(h, attn, sl, sr);
    k_count<<<(kM * kE + 255) / 256, 256, 0, stream>>>(ei, cnt);
    k_scan<<<kM, 1024, 0, stream>>>(cnt, offs);
    k_scatter<<<(kM * kE + 255) / 256, 256, 0, stream>>>(ei, offs, cur, srcsort);
    k_agg<<<kN, 256, 0, stream>>>(h, sl, sr, offs, srcsort, ral, rar, rbias, out);
}

// Round 2
// 765.038 us; speedup vs baseline: 1.3790x; 1.3790x over previous
//
#include <hip/hip_runtime.h>
#include <math.h>

// Problem constants
#define kN 50000
#define kE 800000
#define kM 4
#define kH 4
#define kC 32
#define kIN 256
#define kD 128   // kH*kC

// ---------------------------------------------------------------------------
// zero scratch counters
__global__ void k_zero(int* __restrict__ p, int n) {
    int i = blockIdx.x * blockDim.x + threadIdx.x;
    if (i < n) p[i] = 0;
}

// ---------------------------------------------------------------------------
// h[n][128] = relu(feats[n][256] @ W[256][128] + b)
// block 256 threads, tile 64 rows x 128 cols, k staged in chunks of 64
__global__ __launch_bounds__(256) void k_gemm(const float* __restrict__ feats,
                                              const float* __restrict__ W,
                                              const float* __restrict__ b,
                                              float* __restrict__ h) {
    __shared__ float fr[64][68];    // [row][k], pad 68 to break bank conflicts
    __shared__ float wc[64][128];   // [k][col]
    const int t = threadIdx.x;
    const int rowbase = blockIdx.x * 64;
    const int tr4 = (t >> 4) * 4;   // rows tr4..tr4+3
    const int tc = t & 15;          // cols tc*4..+3 and 64+tc*4..+3

    float acc[4][8];
#pragma unroll
    for (int i = 0; i < 4; i++)
#pragma unroll
        for (int j = 0; j < 8; j++) acc[i][j] = 0.f;

    for (int kc = 0; kc < kIN; kc += 64) {
        // stage feats chunk: 64 rows x 64 k
        {
            const int row = t >> 4;   // 0..15
            const int k4 = t & 15;    // 0..15
#pragma unroll
            for (int i = 0; i < 4; i++) {
                const int r = row + i * 16;
                const int rg = rowbase + r;
                float4 v = make_float4(0.f, 0.f, 0.f, 0.f);
                if (rg < kN)
                    v = *reinterpret_cast<const float4*>(feats + rg * kIN + kc + k4 * 4);
                *reinterpret_cast<float4*>(&fr[r][k4 * 4]) = v;
            }
        }
        // stage W chunk: 64 k x 128 cols
#pragma unroll
        for (int i = 0; i < 8; i++) {
            const int v4 = t + i * 256;   // 0..2047 float4 index
            const int kk = v4 >> 5;       // 0..63
            const int c4 = v4 & 31;       // 0..31
            *reinterpret_cast<float4*>(&wc[kk][c4 * 4]) =
                *reinterpret_cast<const float4*>(W + (size_t)(kc + kk) * kD + c4 * 4);
        }
        __syncthreads();

#pragma unroll 8
        for (int k = 0; k < 64; k++) {
            const float a0 = fr[tr4 + 0][k];
            const float a1 = fr[tr4 + 1][k];
            const float a2 = fr[tr4 + 2][k];
            const float a3 = fr[tr4 + 3][k];
            const float4 w0 = *reinterpret_cast<const float4*>(&wc[k][tc * 4]);
            const float4 w1 = *reinterpret_cast<const float4*>(&wc[k][64 + tc * 4]);
            acc[0][0] += a0 * w0.x; acc[0][1] += a0 * w0.y; acc[0][2] += a0 * w0.z; acc[0][3] += a0 * w0.w;
            acc[0][4] += a0 * w1.x; acc[0][5] += a0 * w1.y; acc[0][6] += a0 * w1.z; acc[0][7] += a0 * w1.w;
            acc[1][0] += a1 * w0.x; acc[1][1] += a1 * w0.y; acc[1][2] += a1 * w0.z; acc[1][3] += a1 * w0.w;
            acc[1][4] += a1 * w1.x; acc[1][5] += a1 * w1.y; acc[1][6] += a1 * w1.z; acc[1][7] += a1 * w1.w;
            acc[2][0] += a2 * w0.x; acc[2][1] += a2 * w0.y; acc[2][2] += a2 * w0.z; acc[2][3] += a2 * w0.w;
            acc[2][4] += a2 * w1.x; acc[2][5] += a2 * w1.y; acc[2][6] += a2 * w1.z; acc[2][7] += a2 * w1.w;
            acc[3][0] += a3 * w0.x; acc[3][1] += a3 * w0.y; acc[3][2] += a3 * w0.z; acc[3][3] += a3 * w0.w;
            acc[3][4] += a3 * w1.x; acc[3][5] += a3 * w1.y; acc[3][6] += a3 * w1.z; acc[3][7] += a3 * w1.w;
        }
        __syncthreads();
    }

    const float4 b0 = *reinterpret_cast<const float4*>(b + tc * 4);
    const float4 b1 = *reinterpret_cast<const float4*>(b + 64 + tc * 4);
#pragma unroll
    for (int i = 0; i < 4; i++) {
        const int rg = rowbase + tr4 + i;
        if (rg < kN) {
            float4 o0, o1;
            o0.x = fmaxf(acc[i][0] + b0.x, 0.f);
            o0.y = fmaxf(acc[i][1] + b0.y, 0.f);
            o0.z = fmaxf(acc[i][2] + b0.z, 0.f);
            o0.w = fmaxf(acc[i][3] + b0.w, 0.f);
            o1.x = fmaxf(acc[i][4] + b1.x, 0.f);
            o1.y = fmaxf(acc[i][5] + b1.y, 0.f);
            o1.z = fmaxf(acc[i][6] + b1.z, 0.f);
            o1.w = fmaxf(acc[i][7] + b1.w, 0.f);
            *reinterpret_cast<float4*>(h + (size_t)rg * kD + tc * 4) = o0;
            *reinterpret_cast<float4*>(h + (size_t)rg * kD + 64 + tc * 4) = o1;
        }
    }
}

// ---------------------------------------------------------------------------
// per-node attention scalars: sl[m][n][h] = h[n,h,:].attn[m,h,:C]
//                             sr[m][n][h] = h[n,h,:].attn[m,h,C:]
__global__ void k_slr(const float* __restrict__ h, const float* __restrict__ attn,
                      float* __restrict__ sl, float* __restrict__ sr) {
    const int id = blockIdx.x * blockDim.x + threadIdx.x;
    if (id >= kN * kH) return;
    const int n = id >> 2;
    const int hh = id & 3;
    float4 hx[8];
    const float4* hv = reinterpret_cast<const float4*>(h + (size_t)n * kD + hh * kC);
#pragma unroll
    for (int i = 0; i < 8; i++) hx[i] = hv[i];
#pragma unroll
    for (int m = 0; m < kM; m++) {
        const float4* al = reinterpret_cast<const float4*>(attn + (m * kH + hh) * 2 * kC);
        const float4* ar = al + 8;
        float s0 = 0.f, s1 = 0.f;
#pragma unroll
        for (int i = 0; i < 8; i++) {
            const float4 a = al[i], r = ar[i], x = hx[i];
            s0 += x.x * a.x + x.y * a.y + x.z * a.z + x.w * a.w;
            s1 += x.x * r.x + x.y * r.y + x.z * r.z + x.w * r.w;
        }
        sl[((size_t)m * kN + n) * kH + hh] = s0;
        sr[((size_t)m * kN + n) * kH + hh] = s1;
    }
}

// ---------------------------------------------------------------------------
// CSR build: degree count
__global__ void k_count(const int* __restrict__ ei, int* __restrict__ cnt) {
    const int e = blockIdx.x * blockDim.x + threadIdx.x;
    if (e >= kM * kE) return;
    const int m = e / kE;
    const int el = e - m * kE;
    const int dst = ei[(size_t)m * 2 * kE + kE + el];
    atomicAdd(&cnt[m * kN + dst], 1);
}

// exclusive scan per metapath (one block per m)
__global__ __launch_bounds__(1024) void k_scan(const int* __restrict__ cnt,
                                               int* __restrict__ offs) {
    const int m = blockIdx.x;
    const int* c = cnt + (size_t)m * kN;
    int* o = offs + (size_t)m * (kN + 1);
    __shared__ int wsum[16];
    __shared__ int carry_s;
    const int t = threadIdx.x;
    const int w = t >> 6, l = t & 63;
    if (t == 0) carry_s = 0;
    __syncthreads();
    for (int base = 0; base < kN; base += 4096) {
        const int i0 = base + t * 4;
        const int v0 = (i0 + 0 < kN) ? c[i0 + 0] : 0;
        const int v1 = (i0 + 1 < kN) ? c[i0 + 1] : 0;
        const int v2 = (i0 + 2 < kN) ? c[i0 + 2] : 0;
        const int v3 = (i0 + 3 < kN) ? c[i0 + 3] : 0;
        const int s = v0 + v1 + v2 + v3;
        int sc = s;
#pragma unroll
        for (int d = 1; d < 64; d <<= 1) {
            const int x = __shfl_up(sc, d);
            if (l >= d) sc += x;
        }
        if (l == 63) wsum[w] = sc;
        __syncthreads();
        int woff = 0, tot = 0;
#pragma unroll
        for (int i = 0; i < 16; i++) {
            const int v = wsum[i];
            tot += v;
            if (i < w) woff += v;
        }
        const int carry = carry_s;
        __syncthreads();
        if (t == 0) carry_s = carry + tot;
        int run = carry + woff + (sc - s);
        if (i0 + 0 < kN) o[i0 + 0] = run; run += v0;
        if (i0 + 1 < kN) o[i0 + 1] = run; run += v1;
        if (i0 + 2 < kN) o[i0 + 2] = run; run += v2;
        if (i0 + 3 < kN) o[i0 + 3] = run; run += v3;
    }
    if (t == 0) o[kN] = carry_s;
}

// scatter src ids into CSR order
__global__ void k_scatter(const int* __restrict__ ei, const int* __restrict__ offs,
                          int* __restrict__ cur, int* __restrict__ srcsort) {
    const int e = blockIdx.x * blockDim.x + threadIdx.x;
    if (e >= kM * kE) return;
    const int m = e / kE;
    const int el = e - m * kE;
    const int src = ei[(size_t)m * 2 * kE + el];
    const int dst = ei[(size_t)m * 2 * kE + kE + el];
    const int pos = offs[(size_t)m * (kN + 1) + dst] + atomicAdd(&cur[m * kN + dst], 1);
    srcsort[(size_t)m * kE + pos] = src;
}

// ---------------------------------------------------------------------------
// main: per-dst-node block; wave m = metapath m. Online-softmax single pass
// with chunked (CH=16) batched gathers for memory-level parallelism, then
// fused beta relation-attention epilogue on wave 0.
#define CH 16
__global__ __launch_bounds__(256) void k_agg(const float* __restrict__ h,
                                             const float* __restrict__ sl,
                                             const float* __restrict__ sr,
                                             const int* __restrict__ offs,
                                             const int* __restrict__ srcsort,
                                             const float* __restrict__ ral,
                                             const float* __restrict__ rar,
                                             const float* __restrict__ rbias,
                                             float* __restrict__ out) {
    const int dst = blockIdx.x;
    const int t = threadIdx.x;
    const int m = t >> 6;
    const int l = t & 63;
    const int hh = l >> 4;        // head for this lane
    const int e0 = l * 2;         // element index (h*32+c), lane covers e0,e0+1

    __shared__ float sm[kM][kD];

    const int beg = offs[(size_t)m * (kN + 1) + dst];
    const int end = offs[(size_t)m * (kN + 1) + dst + 1];
    const int cnt = end - beg;
    const float sl_h = sl[((size_t)m * kN + dst) * kH + hh];
    const int* __restrict__ sbase = srcsort + (size_t)m * kE + beg;
    const float* __restrict__ srm = sr + (size_t)m * kN * kH;

    float maxl = -1e30f, sum = 0.f, a0 = 0.f, a1 = 0.f;

    for (int c = 0; c < cnt; c += CH) {
        const int nb = min(cnt - c, CH);
        // lane-parallel src id load (lanes 0..15)
        int my = 0;
        if (l < CH && c + l < cnt) my = sbase[c + l];
        int sj[CH];
#pragma unroll
        for (int j = 0; j < CH; j++) {
            const int v = __shfl(my, j);
            sj[j] = (j < nb) ? v : dst;   // safe address for invalid slots
        }
        // batched sr gathers (all CH loads in flight)
        float lg[CH];
#pragma unroll
        for (int j = 0; j < CH; j++)
            lg[j] = srm[(size_t)sj[j] * kH + hh];
#pragma unroll
        for (int j = 0; j < CH; j++) {
            float x = sl_h + lg[j];
            x = x > 0.f ? x : 0.2f * x;       // LeakyReLU(0.2)
            lg[j] = (j < nb) ? x : -1e30f;
        }
        float cmax = maxl;
#pragma unroll
        for (int j = 0; j < CH; j++) cmax = fmaxf(cmax, lg[j]);
        const float scale = __expf(maxl - cmax);   // 0 on first chunk (sum==0 anyway)
        maxl = cmax;
        sum *= scale; a0 *= scale; a1 *= scale;
        // batched h gathers (all CH float2 loads in flight; exp overlaps latency)
        float2 hv[CH];
#pragma unroll
        for (int j = 0; j < CH; j++)
            hv[j] = *reinterpret_cast<const float2*>(h + (size_t)sj[j] * kD + e0);
#pragma unroll
        for (int j = 0; j < CH; j++) {
            const float w = __expf(lg[j] - cmax);  // 0 for invalid slots
            sum += w;
            a0 += w * hv[j].x;
            a1 += w * hv[j].y;
        }
    }
    const float inv = sum > 0.f ? 1.0f / sum : 0.f;
    sm[m][e0] = a0 * inv;
    sm[m][e0 + 1] = a1 * inv;
    __syncthreads();

    if (m == 0) {
        const float2 hd = *reinterpret_cast<const float2*>(h + (size_t)dst * kD + e0);
        const float bl0 = fmaxf(hd.x * ral[e0], 0.f);
        const float bl1 = fmaxf(hd.y * ral[e0 + 1], 0.f);
        float emb0[5], emb1[5], beta[5];
#pragma unroll
        for (int r = 0; r < 5; r++) {
            const float x0 = (r < 4) ? sm[r][e0] : hd.x;
            const float x1 = (r < 4) ? sm[r][e0 + 1] : hd.y;
            emb0[r] = x0;
            emb1[r] = x1;
            const float br0 = fmaxf(x0 * rar[r * kD + e0], 0.f);
            const float br1 = fmaxf(x1 * rar[r * kD + e0 + 1], 0.f);
            float p = bl0 * br0 + bl1 * br1;
            p += __shfl_xor(p, 1);
            p += __shfl_xor(p, 2);
            p += __shfl_xor(p, 4);
            p += __shfl_xor(p, 8);
            beta[r] = p + rbias[r];
        }
        float mx = beta[0];
#pragma unroll
        for (int r = 1; r < 5; r++) mx = fmaxf(mx, beta[r]);
        float s = 0.f, wgt[5];
#pragma unroll
        for (int r = 0; r < 5; r++) { wgt[r] = __expf(beta[r] - mx); s += wgt[r]; }
        const float invb = 1.f / s;
        float o0 = 0.f, o1 = 0.f;
#pragma unroll
        for (int r = 0; r < 5; r++) { o0 += emb0[r] * wgt[r]; o1 += emb1[r] * wgt[r]; }
        out[(size_t)dst * kD + e0] = fmaxf(o0 * invb, 0.f);
        out[(size_t)dst * kD + e0 + 1] = fmaxf(o1 * invb, 0.f);
    }
}

// ---------------------------------------------------------------------------
extern "C" void kernel_launch(void* const* d_in, const int* in_sizes, int n_in,
                              void* d_out, int out_size, void* d_ws, size_t ws_size,
                              hipStream_t stream) {
    const float* feats = (const float*)d_in[0];
    const int* ei      = (const int*)d_in[1];
    const float* W     = (const float*)d_in[2];
    const float* b     = (const float*)d_in[3];
    const float* attn  = (const float*)d_in[4];
    const float* ral   = (const float*)d_in[5];
    const float* rar   = (const float*)d_in[6];
    const float* rbias = (const float*)d_in[7];
    float* out = (float*)d_out;

    char* ws = (char*)d_ws;
    size_t off = 0;
    auto alloc = [&](size_t bytes) -> void* {
        void* p = ws + off;
        off = (off + bytes + 255) & ~(size_t)255;
        return p;
    };
    float* h    = (float*)alloc(sizeof(float) * (size_t)kN * kD);          // 25.6 MB
    float* sl   = (float*)alloc(sizeof(float) * (size_t)kM * kN * kH);     // 3.2 MB
    float* sr   = (float*)alloc(sizeof(float) * (size_t)kM * kN * kH);     // 3.2 MB
    int* cnt    = (int*)alloc(sizeof(int) * (size_t)2 * kM * kN);          // cnt+cur
    int* cur    = cnt + (size_t)kM * kN;
    int* offs   = (int*)alloc(sizeof(int) * (size_t)kM * (kN + 1));
    int* srcsort= (int*)alloc(sizeof(int) * (size_t)kM * kE);              // 12.8 MB

    k_zero<<<(2 * kM * kN + 255) / 256, 256, 0, stream>>>(cnt, 2 * kM * kN);
    k_gemm<<<(kN + 63) / 64, 256, 0, stream>>>(feats, W, b, h);
    k_slr<<<(kN * kH + 255) / 256, 256, 0, stream>>>(h, attn, sl, sr);
    k_count<<<(kM * kE + 255) / 256, 256, 0, stream>>>(ei, cnt);
    k_scan<<<kM, 1024, 0, stream>>>(cnt, offs);
    k_scatter<<<(kM * kE + 255) / 256, 256, 0, stream>>>(ei, offs, cur, srcsort);
    k_agg<<<kN, 256, 0, stream>>>(h, sl, sr, offs, srcsort, ral, rar, rbias, out);
}